// Round 11
// baseline (148.179 us; speedup 1.0000x reference)
//
#include <hip/hip_runtime.h>
#include <hip/hip_bf16.h>

typedef short bf16x8 __attribute__((ext_vector_type(8)));
typedef unsigned short u16x8 __attribute__((ext_vector_type(8)));
typedef float f32x4 __attribute__((ext_vector_type(4)));

#define LQ 300
#define LV 21760
#define NQ 2400      // bs * LQ
#define MROWS 174080 // bs * LV

#define VBM 64            // rows per gemm tile
#define VGRID 256         // persistent gemm blocks (1/CU)
#define VNT (MROWS / VBM) // 2720 tiles

__device__ __forceinline__ unsigned short f2bf(float x) {
    __hip_bfloat16 h = __float2bfloat16(x);
    return *reinterpret_cast<unsigned short*>(&h);
}
__device__ __forceinline__ float bf2f(unsigned short s) {
    return __uint_as_float(((unsigned)s) << 16);
}
__device__ __forceinline__ bf16x8 cvt8(float4 a, float4 b) {
    u16x8 u;
    u[0] = f2bf(a.x); u[1] = f2bf(a.y); u[2] = f2bf(a.z); u[3] = f2bf(a.w);
    u[4] = f2bf(b.x); u[5] = f2bf(b.y); u[6] = f2bf(b.z); u[7] = f2bf(b.w);
    return (bf16x8)u;
}
__device__ __forceinline__ bf16x8 cvt8v(f32x4 a, f32x4 b) {
    u16x8 u;
    u[0] = f2bf(a[0]); u[1] = f2bf(a[1]); u[2] = f2bf(a[2]); u[3] = f2bf(a[3]);
    u[4] = f2bf(b[0]); u[5] = f2bf(b[1]); u[6] = f2bf(b[2]); u[7] = f2bf(b[3]);
    return (bf16x8)u;
}

// ---------------------------------------------------------------- K1: weight transpose+convert to bf16 [n][k]
__global__ void k_wt(const float* __restrict__ Wv, const float* __restrict__ Woff,
                     const float* __restrict__ Wattn, const float* __restrict__ Wout,
                     unsigned short* __restrict__ ws) {
    int i = blockIdx.x * 256 + threadIdx.x;   // 229376 total
    if (i < 65536) {
        int n = i >> 8, k = i & 255;
        ws[i] = f2bf(Wv[k * 256 + n]);
    } else if (i < 65536 + 98304) {
        int j = i - 65536;
        int n = j >> 8, k = j & 255;
        float s = (n < 256) ? Woff[k * 256 + n] : Wattn[k * 128 + (n - 256)];
        ws[i] = f2bf(s);
    } else {
        int j = i - 163840;
        int n = j >> 8, k = j & 255;
        ws[i] = f2bf(Wout[k * 256 + n]);
    }
}

// ---------------------------------------------------------------- K2: V = bf16(value) @ Wt + b  (STANDALONE — no co-compiled paths)
// Persistent, 1 block/CU, 512 thr = 8 waves (2 row x 4 col groups).
// VBM=64: per-tile compute (~2000 cy) >> HBM latency (~900 cy) -> depth-1
// prefetch fully hides the stream. B frags in registers. Counted vmcnt.
__global__ __launch_bounds__(512, 2) void k_vgemm(
    const float* __restrict__ A, const unsigned short* __restrict__ Bt,
    const float* __restrict__ bias, unsigned short* __restrict__ V)
{
    __shared__ __align__(16) float buf[2][VBM * 256];   // 2 x 64 KB
    const int t = threadIdx.x;
    const int lane = t & 63;
    const int wv = t >> 6;                  // 0..7
    const int wr = wv >> 2, wc = wv & 3;    // row group (32 rows), col group (64 cols)
    const int fr = lane & 15, kg = lane >> 4;

    // ---- B preload: col-group's 64 cols x K=256 -> 32 frags (128 VGPR)
    bf16x8 bw[8][4];
#pragma unroll
    for (int kk = 0; kk < 8; ++kk)
#pragma unroll
        for (int n = 0; n < 4; ++n)
            bw[kk][n] = *(const bf16x8*)(Bt + (size_t)(wc * 64 + n * 16 + fr) * 256 + kk * 32 + kg * 8);
    float bv[4];
#pragma unroll
    for (int n = 0; n < 4; ++n) bv[n] = bias[wc * 64 + n * 16 + fr];

    // stage one 64x256 f32 tile: 8 rows/wave, 1 KB/instr, linear dest, src pre-swizzled
#define VSTAGE(tile, cb)                                                                  \
    {                                                                                     \
        const char* tb = (const char*)(A + (size_t)(tile) * (VBM * 256));                 \
        _Pragma("unroll")                                                                 \
        for (int i = 0; i < 8; ++i) {                                                     \
            const int r = wv * 8 + i;                                                     \
            __builtin_amdgcn_global_load_lds(                                             \
                (const __attribute__((address_space(1))) void*)                           \
                    (tb + (size_t)r * 1024 + ((lane * 16) ^ ((r & 7) << 4))),             \
                (__attribute__((address_space(3))) void*)&buf[cb][r * 256], 16, 0, 0);    \
        }                                                                                 \
    }

    const int tb0 = (int)blockIdx.x;
    VSTAGE(tb0, 0);

    int cur = 0;
    for (int tile = tb0; tile < VNT; tile += VGRID, cur ^= 1) {
        const int nxt = tile + VGRID;
        const bool stged = (nxt < VNT);
        if (stged) VSTAGE(nxt, cur ^ 1);
        // ensure loads(tile) done; leave stores(prev)[4] + loads(next)[8] in flight
        if (tile == tb0) {
            if (stged) asm volatile("s_waitcnt vmcnt(8)" ::: "memory");
            else       asm volatile("s_waitcnt vmcnt(0)" ::: "memory");
        } else {
            if (stged) asm volatile("s_waitcnt vmcnt(12)" ::: "memory");
            else       asm volatile("s_waitcnt vmcnt(4)" ::: "memory");
        }
        __builtin_amdgcn_s_barrier();

        const float* lp = buf[cur];
        f32x4 acc[2][4];
#pragma unroll
        for (int m = 0; m < 2; ++m)
#pragma unroll
            for (int n = 0; n < 4; ++n) { f32x4 z = {0.f, 0.f, 0.f, 0.f}; acc[m][n] = z; }

#pragma unroll
        for (int kk = 0; kk < 8; ++kk) {
            bf16x8 a[2];
#pragma unroll
            for (int m = 0; m < 2; ++m) {
                const int row = wr * 32 + m * 16 + fr;
                const int bsw = ((kk * 32 + kg * 8) * 4) ^ ((row & 7) << 4);
                f32x4 af0 = *(const f32x4*)((const char*)(lp + row * 256) + bsw);
                f32x4 af1 = *(const f32x4*)((const char*)(lp + row * 256) + (bsw ^ 16));
                a[m] = cvt8v(af0, af1);
            }
#pragma unroll
            for (int m = 0; m < 2; ++m)
#pragma unroll
                for (int n = 0; n < 4; ++n)
                    acc[m][n] = __builtin_amdgcn_mfma_f32_16x16x32_bf16(a[m], bw[kk][n], acc[m][n], 0, 0, 0);
        }

        __builtin_amdgcn_s_barrier();            // all waves done reading A(tile)

        unsigned short* cp = (unsigned short*)buf[cur];  // C tile [64][264] bf16 (padded)
#pragma unroll
        for (int n = 0; n < 4; ++n)
#pragma unroll
            for (int m = 0; m < 2; ++m)
#pragma unroll
                for (int r = 0; r < 4; ++r)
                    cp[(wr * 32 + m * 16 + kg * 4 + r) * 264 + wc * 64 + n * 16 + fr] =
                        f2bf(acc[m][n][r] + bv[n]);
        asm volatile("s_waitcnt lgkmcnt(0)" ::: "memory");
        __builtin_amdgcn_sched_barrier(0);
        __builtin_amdgcn_s_barrier();            // C tile visible to all waves

        unsigned short* ob = V + (size_t)tile * (VBM * 256);
#pragma unroll
        for (int i = 0; i < 4; ++i) {
            const int f = i * 512 + t;           // 8-u16 group index (2048 groups)
            const int row = f >> 5, col = (f & 31) * 8;
            *(u16x8*)(ob + row * 256 + col) = *(const u16x8*)&cp[row * 264 + col];
        }
        __builtin_amdgcn_s_barrier();            // reads of buf[cur] done before its next DMA overwrite
    }
#undef VSTAGE
}

// ---------------------------------------------------------------- K3: [off|attn] = query @ [W_off|W_attn] + bias
__global__ __launch_bounds__(512) void k_qproj(
    const float* __restrict__ Q, const unsigned short* __restrict__ Woa,
    const float* __restrict__ b_off, const float* __restrict__ b_attn,
    float* __restrict__ offattn)
{
    const int t = threadIdx.x;
    const int lane = t & 63;
    const int wid = t >> 6;
    const int wr = wid >> 2, wc = wid & 3;
    const int fr = lane & 15, kg = lane >> 4;
    const int rowBase = blockIdx.x * 64;

    const int r0 = min(rowBase + wr * 32 + fr, NQ - 1);
    const int r1 = min(rowBase + wr * 32 + 16 + fr, NQ - 1);

    f32x4 acc[2][6];
#pragma unroll
    for (int m = 0; m < 2; m++)
#pragma unroll
        for (int n = 0; n < 6; n++) { f32x4 z = {0.f, 0.f, 0.f, 0.f}; acc[m][n] = z; }

#pragma unroll
    for (int kk = 0; kk < 8; ++kk) {
        const int kb = kk * 32 + kg * 8;
        float4 q00 = *(const float4*)(Q + (size_t)r0 * 256 + kb);
        float4 q01 = *(const float4*)(Q + (size_t)r0 * 256 + kb + 4);
        float4 q10 = *(const float4*)(Q + (size_t)r1 * 256 + kb);
        float4 q11 = *(const float4*)(Q + (size_t)r1 * 256 + kb + 4);
        bf16x8 a0 = cvt8(q00, q01);
        bf16x8 a1 = cvt8(q10, q11);
#pragma unroll
        for (int n = 0; n < 6; n++) {
            bf16x8 bb = *(const bf16x8*)(Woa + (size_t)(wc * 96 + n * 16 + fr) * 256 + kb);
            acc[0][n] = __builtin_amdgcn_mfma_f32_16x16x32_bf16(a0, bb, acc[0][n], 0, 0, 0);
            acc[1][n] = __builtin_amdgcn_mfma_f32_16x16x32_bf16(a1, bb, acc[1][n], 0, 0, 0);
        }
    }

#pragma unroll
    for (int m = 0; m < 2; m++) {
#pragma unroll
        for (int n = 0; n < 6; n++) {
            int col = wc * 96 + n * 16 + fr;
            float bvv = (col < 256) ? b_off[col] : b_attn[col - 256];
#pragma unroll
            for (int r = 0; r < 4; r++) {
                int row = rowBase + wr * 32 + m * 16 + kg * 4 + r;
                if (row < NQ) offattn[(size_t)row * 384 + col] = acc[m][n][r] + bvv;
            }
        }
    }
}

// ---------------------------------------------------------------- K4: softmax + grid + gather + fused out-proj
// 1 block = 2 queries; gather: 128 thr/query (1 head, 2 channels each);
// out phase: att rows in LDS (f32), thread t -> out col t for both rows.
__global__ __launch_bounds__(256) void k_sample(
    const float* __restrict__ refp, const float* __restrict__ offattn,
    const unsigned short* __restrict__ V, const unsigned short* __restrict__ Wout,
    const float* __restrict__ b_out, float* __restrict__ out)
{
    __shared__ float aw[2][128], gx[2][128], gy[2][128];
    __shared__ float att_s[2][256];
    const int t = threadIdx.x;
    const int jj = t >> 7;               // query slot in block
    const int tt = t & 127;
    const int row = blockIdx.x * 2 + jj; // global query index
    const int b = row / LQ;
    const float* oa = offattn + (size_t)row * 384;

    {   // setup: thread (jj,tt) handles point tt of query jj
        float logit = oa[256 + tt];
        float m = logit;
        m = fmaxf(m, __shfl_xor(m, 1));
        m = fmaxf(m, __shfl_xor(m, 2));
        m = fmaxf(m, __shfl_xor(m, 4));
        m = fmaxf(m, __shfl_xor(m, 8));
        float e = __expf(logit - m);
        float s = e;
        s += __shfl_xor(s, 1);
        s += __shfl_xor(s, 2);
        s += __shfl_xor(s, 4);
        s += __shfl_xor(s, 8);
        aw[jj][tt] = e / s;
        const int l = (tt >> 2) & 3;
        const float Wl = (l == 0) ? 128.f : (l == 1) ? 64.f : (l == 2) ? 32.f : 16.f;
        float ox = oa[2 * tt], oy = oa[2 * tt + 1];
        const float* rp = refp + ((size_t)row * 4 + l) * 4;
        gx[jj][tt] = (rp[0] + ox * 0.125f * rp[2]) * Wl - 0.5f;
        gy[jj][tt] = (rp[1] + oy * 0.125f * rp[3]) * Wl - 0.5f;
    }
    __syncthreads();

    const int h = tt >> 4;                  // head
    const int ch = h * 32 + (tt & 15) * 2;  // channel pair base
    float acc0 = 0.f, acc1 = 0.f;
#pragma unroll 4
    for (int p = 0; p < 16; p++) {
        const int l = p >> 2;
        const int Wl = (l == 0) ? 128 : (l == 1) ? 64 : (l == 2) ? 32 : 16;
        const int S  = (l == 0) ? 0 : (l == 1) ? 16384 : (l == 2) ? 20480 : 21504;
        int pt = h * 16 + p;
        float a  = aw[jj][pt];
        float sx = gx[jj][pt], sy = gy[jj][pt];
        float x0f = floorf(sx), y0f = floorf(sy);
        int   x0 = (int)x0f, y0 = (int)y0f;
        float wx1 = sx - x0f, wy1 = sy - y0f;
        float wx0 = 1.f - wx1, wy0 = 1.f - wy1;
        bool vx0 = (unsigned)x0 < (unsigned)Wl;
        bool vx1 = (unsigned)(x0 + 1) < (unsigned)Wl;
        bool vy0 = (unsigned)y0 < (unsigned)Wl;
        bool vy1 = (unsigned)(y0 + 1) < (unsigned)Wl;
        float p00x = 0.f, p00y = 0.f, p01x = 0.f, p01y = 0.f;
        float p10x = 0.f, p10y = 0.f, p11x = 0.f, p11y = 0.f;
        size_t pixBase = (size_t)b * LV + S;
        if (vy0) {
            size_t rb = (pixBase + (size_t)y0 * Wl) * 256 + ch;
            if (vx0) { unsigned u = *(const unsigned*)(V + rb + (size_t)x0 * 256);
                       p00x = bf2f((unsigned short)u); p00y = bf2f((unsigned short)(u >> 16)); }
            if (vx1) { unsigned u = *(const unsigned*)(V + rb + (size_t)x0 * 256 + 256);
                       p01x = bf2f((unsigned short)u); p01y = bf2f((unsigned short)(u >> 16)); }
        }
        if (vy1) {
            size_t rb = (pixBase + (size_t)(y0 + 1) * Wl) * 256 + ch;
            if (vx0) { unsigned u = *(const unsigned*)(V + rb + (size_t)x0 * 256);
                       p10x = bf2f((unsigned short)u); p10y = bf2f((unsigned short)(u >> 16)); }
            if (vx1) { unsigned u = *(const unsigned*)(V + rb + (size_t)x0 * 256 + 256);
                       p11x = bf2f((unsigned short)u); p11y = bf2f((unsigned short)(u >> 16)); }
        }
        acc0 += a * (wy0 * (wx0 * p00x + wx1 * p01x) + wy1 * (wx0 * p10x + wx1 * p11x));
        acc1 += a * (wy0 * (wx0 * p00y + wx1 * p01y) + wy1 * (wx0 * p10y + wx1 * p11y));
    }
    att_s[jj][ch] = acc0;
    att_s[jj][ch + 1] = acc1;
    __syncthreads();

    // ---- fused out-projection: thread t computes out[row0][t], out[row1][t]
    const size_t r0 = (size_t)blockIdx.x * 2;
    float o0 = b_out[t], o1 = o0;
    const unsigned short* wrow = Wout + (size_t)t * 256;   // Wt_out[t][k]
#pragma unroll 8
    for (int k = 0; k < 256; k += 8) {
        bf16x8 w8 = *(const bf16x8*)(wrow + k);
#pragma unroll
        for (int e = 0; e < 8; ++e) {
            float w = bf2f((unsigned short)w8[e]);
            o0 += att_s[0][k + e] * w;
            o1 += att_s[1][k + e] * w;
        }
    }
    out[r0 * 256 + t] = o0;
    out[(r0 + 1) * 256 + t] = o1;
}

// ----------------------------------------------------------------
extern "C" void kernel_launch(void* const* d_in, const int* in_sizes, int n_in,
                              void* d_out, int out_size, void* d_ws, size_t ws_size,
                              hipStream_t stream) {
    const float* query   = (const float*)d_in[0];
    const float* refp    = (const float*)d_in[1];
    const float* value   = (const float*)d_in[2];
    const float* W_value = (const float*)d_in[3];
    const float* b_value = (const float*)d_in[4];
    const float* W_off   = (const float*)d_in[5];
    const float* b_off   = (const float*)d_in[6];
    const float* W_attn  = (const float*)d_in[7];
    const float* b_attn  = (const float*)d_in[8];
    const float* W_out   = (const float*)d_in[9];
    const float* b_out   = (const float*)d_in[10];
    float* out = (float*)d_out;

    unsigned short* wsu   = (unsigned short*)d_ws;
    unsigned short* Wt_v  = wsu;                       // 65536
    unsigned short* Wt_oa = Wt_v + 65536;              // 98304
    unsigned short* Wt_out= Wt_oa + 98304;             // 65536
    unsigned short* V     = Wt_out + 65536;            // 174080*256 bf16
    float* offattn = (float*)(V + (size_t)MROWS * 256);     // 2400*384 f32

    k_wt<<<896, 256, 0, stream>>>(W_value, W_off, W_attn, W_out, wsu);
    k_qproj<<<38, 512, 0, stream>>>(query, Wt_oa, b_off, b_attn, offattn);
    k_vgemm<<<VGRID, 512, 0, stream>>>(value, Wt_v, b_value, V);
    k_sample<<<NQ / 2, 256, 0, stream>>>(refp, offattn, V, Wt_out, b_out, out);
}

// Round 12
// 145.945 us; speedup vs baseline: 1.0153x; 1.0153x over previous
//
#include <hip/hip_runtime.h>
#include <hip/hip_bf16.h>

typedef short bf16x8 __attribute__((ext_vector_type(8)));
typedef unsigned short u16x8 __attribute__((ext_vector_type(8)));
typedef float f32x4 __attribute__((ext_vector_type(4)));

#define LQ 300
#define LV 21760
#define NQ 2400      // bs * LQ
#define MROWS 174080 // bs * LV

#define VBM 32            // rows per gemm tile
#define VGRID 512         // persistent gemm blocks (2/CU)
#define VNT (MROWS / VBM) // 5440 tiles

__device__ __forceinline__ unsigned short f2bf(float x) {
    __hip_bfloat16 h = __float2bfloat16(x);
    return *reinterpret_cast<unsigned short*>(&h);
}
__device__ __forceinline__ float bf2f(unsigned short s) {
    return __uint_as_float(((unsigned)s) << 16);
}
__device__ __forceinline__ bf16x8 cvt8(float4 a, float4 b) {
    u16x8 u;
    u[0] = f2bf(a.x); u[1] = f2bf(a.y); u[2] = f2bf(a.z); u[3] = f2bf(a.w);
    u[4] = f2bf(b.x); u[5] = f2bf(b.y); u[6] = f2bf(b.z); u[7] = f2bf(b.w);
    return (bf16x8)u;
}
__device__ __forceinline__ bf16x8 cvt8v(f32x4 a, f32x4 b) {
    u16x8 u;
    u[0] = f2bf(a[0]); u[1] = f2bf(a[1]); u[2] = f2bf(a[2]); u[3] = f2bf(a[3]);
    u[4] = f2bf(b[0]); u[5] = f2bf(b[1]); u[6] = f2bf(b[2]); u[7] = f2bf(b[3]);
    return (bf16x8)u;
}

// ---------------------------------------------------------------- K1: weight transpose+convert to bf16 [n][k]
__global__ void k_wt(const float* __restrict__ Wv, const float* __restrict__ Woff,
                     const float* __restrict__ Wattn, const float* __restrict__ Wout,
                     unsigned short* __restrict__ ws) {
    int i = blockIdx.x * 256 + threadIdx.x;   // 229376 total
    if (i < 65536) {
        int n = i >> 8, k = i & 255;
        ws[i] = f2bf(Wv[k * 256 + n]);
    } else if (i < 65536 + 98304) {
        int j = i - 65536;
        int n = j >> 8, k = j & 255;
        float s = (n < 256) ? Woff[k * 256 + n] : Wattn[k * 128 + (n - 256)];
        ws[i] = f2bf(s);
    } else {
        int j = i - 163840;
        int n = j >> 8, k = j & 255;
        ws[i] = f2bf(Wout[k * 256 + n]);
    }
}

// ---------------------------------------------------------------- K2: V = bf16(value) @ Wt + b (round-9 proven config)
// Persistent, 2 blocks/CU (inter-block overlap covers barrier bubbles).
// f32 A via global_load_lds (pre-swizzled src, rule #21), cvt at frag read,
// B frags in registers, counted vmcnt (stores+loads accounted).
__global__ __launch_bounds__(256, 2) void k_vgemm(
    const float* __restrict__ A, const unsigned short* __restrict__ Bt,
    const float* __restrict__ bias, unsigned short* __restrict__ V)
{
    __shared__ __align__(16) float buf[2][VBM * 256];   // 2 x 32 KB
    const int t = threadIdx.x;
    const int lane = t & 63;
    const int wv = t >> 6;                  // wave = 64-col group
    const int fr = lane & 15, kg = lane >> 4;

    bf16x8 bw[8][4];
#pragma unroll
    for (int kk = 0; kk < 8; ++kk)
#pragma unroll
        for (int n = 0; n < 4; ++n)
            bw[kk][n] = *(const bf16x8*)(Bt + (size_t)(wv * 64 + n * 16 + fr) * 256 + kk * 32 + kg * 8);
    float bv[4];
#pragma unroll
    for (int n = 0; n < 4; ++n) bv[n] = bias[wv * 64 + n * 16 + fr];

#define VSTAGE(tile, cb)                                                                  \
    {                                                                                     \
        const char* tb = (const char*)(A + (size_t)(tile) * (VBM * 256));                 \
        _Pragma("unroll")                                                                 \
        for (int i = 0; i < 8; ++i) {                                                     \
            const int r = wv * 8 + i;                                                     \
            __builtin_amdgcn_global_load_lds(                                             \
                (const __attribute__((address_space(1))) void*)                           \
                    (tb + (size_t)r * 1024 + ((lane * 16) ^ ((r & 7) << 4))),             \
                (__attribute__((address_space(3))) void*)&buf[cb][r * 256], 16, 0, 0);    \
        }                                                                                 \
    }

    const int tb0 = (int)blockIdx.x;
    VSTAGE(tb0, 0);

    int cur = 0;
    for (int tile = tb0; tile < VNT; tile += VGRID, cur ^= 1) {
        const int nxt = tile + VGRID;
        const bool stged = (nxt < VNT);
        if (stged) VSTAGE(nxt, cur ^ 1);
        if (tile == tb0) {
            if (stged) asm volatile("s_waitcnt vmcnt(8)" ::: "memory");
            else       asm volatile("s_waitcnt vmcnt(0)" ::: "memory");
        } else {
            if (stged) asm volatile("s_waitcnt vmcnt(12)" ::: "memory");
            else       asm volatile("s_waitcnt vmcnt(4)" ::: "memory");
        }
        __builtin_amdgcn_s_barrier();

        const float* lp = buf[cur];
        f32x4 acc[2][4];
#pragma unroll
        for (int m = 0; m < 2; ++m)
#pragma unroll
            for (int n = 0; n < 4; ++n) { f32x4 z = {0.f, 0.f, 0.f, 0.f}; acc[m][n] = z; }

#pragma unroll
        for (int kk = 0; kk < 8; ++kk) {
            bf16x8 a[2];
#pragma unroll
            for (int m = 0; m < 2; ++m) {
                const int row = m * 16 + fr;
                const int bsw = ((kk * 32 + kg * 8) * 4) ^ ((row & 7) << 4);
                f32x4 af0 = *(const f32x4*)((const char*)(lp + row * 256) + bsw);
                f32x4 af1 = *(const f32x4*)((const char*)(lp + row * 256) + (bsw ^ 16));
                a[m] = cvt8v(af0, af1);
            }
#pragma unroll
            for (int m = 0; m < 2; ++m)
#pragma unroll
                for (int n = 0; n < 4; ++n)
                    acc[m][n] = __builtin_amdgcn_mfma_f32_16x16x32_bf16(a[m], bw[kk][n], acc[m][n], 0, 0, 0);
        }

        __builtin_amdgcn_s_barrier();

        unsigned short* cp = (unsigned short*)buf[cur];  // C tile [32][264] bf16 (padded)
#pragma unroll
        for (int n = 0; n < 4; ++n)
#pragma unroll
            for (int m = 0; m < 2; ++m)
#pragma unroll
                for (int r = 0; r < 4; ++r)
                    cp[(m * 16 + kg * 4 + r) * 264 + wv * 64 + n * 16 + fr] =
                        f2bf(acc[m][n][r] + bv[n]);
        asm volatile("s_waitcnt lgkmcnt(0)" ::: "memory");
        __builtin_amdgcn_sched_barrier(0);
        __builtin_amdgcn_s_barrier();

        unsigned short* ob = V + (size_t)tile * (VBM * 256);
#pragma unroll
        for (int i = 0; i < 4; ++i) {
            const int f = i * 256 + t;
            const int row = f >> 5, col = (f & 31) * 8;
            *(u16x8*)(ob + row * 256 + col) = *(const u16x8*)&cp[row * 264 + col];
        }
        __builtin_amdgcn_s_barrier();
    }
#undef VSTAGE
}

// ---------------------------------------------------------------- K3: [off|attn] = query @ [W_off|W_attn] + bias
__global__ __launch_bounds__(512) void k_qproj(
    const float* __restrict__ Q, const unsigned short* __restrict__ Woa,
    const float* __restrict__ b_off, const float* __restrict__ b_attn,
    float* __restrict__ offattn)
{
    const int t = threadIdx.x;
    const int lane = t & 63;
    const int wid = t >> 6;
    const int wr = wid >> 2, wc = wid & 3;
    const int fr = lane & 15, kg = lane >> 4;
    const int rowBase = blockIdx.x * 64;

    const int r0 = min(rowBase + wr * 32 + fr, NQ - 1);
    const int r1 = min(rowBase + wr * 32 + 16 + fr, NQ - 1);

    f32x4 acc[2][6];
#pragma unroll
    for (int m = 0; m < 2; m++)
#pragma unroll
        for (int n = 0; n < 6; n++) { f32x4 z = {0.f, 0.f, 0.f, 0.f}; acc[m][n] = z; }

#pragma unroll
    for (int kk = 0; kk < 8; ++kk) {
        const int kb = kk * 32 + kg * 8;
        float4 q00 = *(const float4*)(Q + (size_t)r0 * 256 + kb);
        float4 q01 = *(const float4*)(Q + (size_t)r0 * 256 + kb + 4);
        float4 q10 = *(const float4*)(Q + (size_t)r1 * 256 + kb);
        float4 q11 = *(const float4*)(Q + (size_t)r1 * 256 + kb + 4);
        bf16x8 a0 = cvt8(q00, q01);
        bf16x8 a1 = cvt8(q10, q11);
#pragma unroll
        for (int n = 0; n < 6; n++) {
            bf16x8 bb = *(const bf16x8*)(Woa + (size_t)(wc * 96 + n * 16 + fr) * 256 + kb);
            acc[0][n] = __builtin_amdgcn_mfma_f32_16x16x32_bf16(a0, bb, acc[0][n], 0, 0, 0);
            acc[1][n] = __builtin_amdgcn_mfma_f32_16x16x32_bf16(a1, bb, acc[1][n], 0, 0, 0);
        }
    }

#pragma unroll
    for (int m = 0; m < 2; m++) {
#pragma unroll
        for (int n = 0; n < 6; n++) {
            int col = wc * 96 + n * 16 + fr;
            float bvv = (col < 256) ? b_off[col] : b_attn[col - 256];
#pragma unroll
            for (int r = 0; r < 4; r++) {
                int row = rowBase + wr * 32 + m * 16 + kg * 4 + r;
                if (row < NQ) offattn[(size_t)row * 384 + col] = acc[m][n][r] + bvv;
            }
        }
    }
}

// ---------------------------------------------------------------- K4: softmax + grid + gather + fused out-proj
// 1 block = 2 queries; gather: 128 thr/query (1 head, 2 channels each);
// out phase: att rows in LDS (f32), thread t -> out col t for both rows.
__global__ __launch_bounds__(256) void k_sample(
    const float* __restrict__ refp, const float* __restrict__ offattn,
    const unsigned short* __restrict__ V, const unsigned short* __restrict__ Wout,
    const float* __restrict__ b_out, float* __restrict__ out)
{
    __shared__ float aw[2][128], gx[2][128], gy[2][128];
    __shared__ float att_s[2][256];
    const int t = threadIdx.x;
    const int jj = t >> 7;               // query slot in block
    const int tt = t & 127;
    const int row = blockIdx.x * 2 + jj; // global query index
    const int b = row / LQ;
    const float* oa = offattn + (size_t)row * 384;

    {   // setup: thread (jj,tt) handles point tt of query jj
        float logit = oa[256 + tt];
        float m = logit;
        m = fmaxf(m, __shfl_xor(m, 1));
        m = fmaxf(m, __shfl_xor(m, 2));
        m = fmaxf(m, __shfl_xor(m, 4));
        m = fmaxf(m, __shfl_xor(m, 8));
        float e = __expf(logit - m);
        float s = e;
        s += __shfl_xor(s, 1);
        s += __shfl_xor(s, 2);
        s += __shfl_xor(s, 4);
        s += __shfl_xor(s, 8);
        aw[jj][tt] = e / s;
        const int l = (tt >> 2) & 3;
        const float Wl = (l == 0) ? 128.f : (l == 1) ? 64.f : (l == 2) ? 32.f : 16.f;
        float ox = oa[2 * tt], oy = oa[2 * tt + 1];
        const float* rp = refp + ((size_t)row * 4 + l) * 4;
        gx[jj][tt] = (rp[0] + ox * 0.125f * rp[2]) * Wl - 0.5f;
        gy[jj][tt] = (rp[1] + oy * 0.125f * rp[3]) * Wl - 0.5f;
    }
    __syncthreads();

    const int h = tt >> 4;                  // head
    const int ch = h * 32 + (tt & 15) * 2;  // channel pair base
    float acc0 = 0.f, acc1 = 0.f;
#pragma unroll 4
    for (int p = 0; p < 16; p++) {
        const int l = p >> 2;
        const int Wl = (l == 0) ? 128 : (l == 1) ? 64 : (l == 2) ? 32 : 16;
        const int S  = (l == 0) ? 0 : (l == 1) ? 16384 : (l == 2) ? 20480 : 21504;
        int pt = h * 16 + p;
        float a  = aw[jj][pt];
        float sx = gx[jj][pt], sy = gy[jj][pt];
        float x0f = floorf(sx), y0f = floorf(sy);
        int   x0 = (int)x0f, y0 = (int)y0f;
        float wx1 = sx - x0f, wy1 = sy - y0f;
        float wx0 = 1.f - wx1, wy0 = 1.f - wy1;
        bool vx0 = (unsigned)x0 < (unsigned)Wl;
        bool vx1 = (unsigned)(x0 + 1) < (unsigned)Wl;
        bool vy0 = (unsigned)y0 < (unsigned)Wl;
        bool vy1 = (unsigned)(y0 + 1) < (unsigned)Wl;
        float p00x = 0.f, p00y = 0.f, p01x = 0.f, p01y = 0.f;
        float p10x = 0.f, p10y = 0.f, p11x = 0.f, p11y = 0.f;
        size_t pixBase = (size_t)b * LV + S;
        if (vy0) {
            size_t rb = (pixBase + (size_t)y0 * Wl) * 256 + ch;
            if (vx0) { unsigned u = *(const unsigned*)(V + rb + (size_t)x0 * 256);
                       p00x = bf2f((unsigned short)u); p00y = bf2f((unsigned short)(u >> 16)); }
            if (vx1) { unsigned u = *(const unsigned*)(V + rb + (size_t)x0 * 256 + 256);
                       p01x = bf2f((unsigned short)u); p01y = bf2f((unsigned short)(u >> 16)); }
        }
        if (vy1) {
            size_t rb = (pixBase + (size_t)(y0 + 1) * Wl) * 256 + ch;
            if (vx0) { unsigned u = *(const unsigned*)(V + rb + (size_t)x0 * 256);
                       p10x = bf2f((unsigned short)u); p10y = bf2f((unsigned short)(u >> 16)); }
            if (vx1) { unsigned u = *(const unsigned*)(V + rb + (size_t)x0 * 256 + 256);
                       p11x = bf2f((unsigned short)u); p11y = bf2f((unsigned short)(u >> 16)); }
        }
        acc0 += a * (wy0 * (wx0 * p00x + wx1 * p01x) + wy1 * (wx0 * p10x + wx1 * p11x));
        acc1 += a * (wy0 * (wx0 * p00y + wx1 * p01y) + wy1 * (wx0 * p10y + wx1 * p11y));
    }
    att_s[jj][ch] = acc0;
    att_s[jj][ch + 1] = acc1;
    __syncthreads();

    // ---- fused out-projection: thread t computes out[row0][t], out[row1][t]
    const size_t r0 = (size_t)blockIdx.x * 2;
    float o0 = b_out[t], o1 = o0;
    const unsigned short* wrow = Wout + (size_t)t * 256;   // Wt_out[t][k]
#pragma unroll 8
    for (int k = 0; k < 256; k += 8) {
        bf16x8 w8 = *(const bf16x8*)(wrow + k);
#pragma unroll
        for (int e = 0; e < 8; ++e) {
            float w = bf2f((unsigned short)w8[e]);
            o0 += att_s[0][k + e] * w;
            o1 += att_s[1][k + e] * w;
        }
    }
    out[r0 * 256 + t] = o0;
    out[(r0 + 1) * 256 + t] = o1;
}

// ----------------------------------------------------------------
extern "C" void kernel_launch(void* const* d_in, const int* in_sizes, int n_in,
                              void* d_out, int out_size, void* d_ws, size_t ws_size,
                              hipStream_t stream) {
    const float* query   = (const float*)d_in[0];
    const float* refp    = (const float*)d_in[1];
    const float* value   = (const float*)d_in[2];
    const float* W_value = (const float*)d_in[3];
    const float* b_value = (const float*)d_in[4];
    const float* W_off   = (const float*)d_in[5];
    const float* b_off   = (const float*)d_in[6];
    const float* W_attn  = (const float*)d_in[7];
    const float* b_attn  = (const float*)d_in[8];
    const float* W_out   = (const float*)d_in[9];
    const float* b_out   = (const float*)d_in[10];
    float* out = (float*)d_out;

    unsigned short* wsu   = (unsigned short*)d_ws;
    unsigned short* Wt_v  = wsu;                       // 65536
    unsigned short* Wt_oa = Wt_v + 65536;              // 98304
    unsigned short* Wt_out= Wt_oa + 98304;             // 65536
    unsigned short* V     = Wt_out + 65536;            // 174080*256 bf16
    float* offattn = (float*)(V + (size_t)MROWS * 256);     // 2400*384 f32

    k_wt<<<896, 256, 0, stream>>>(W_value, W_off, W_attn, W_out, wsu);
    k_qproj<<<38, 512, 0, stream>>>(query, Wt_oa, b_off, b_attn, offattn);
    k_vgemm<<<VGRID, 256, 0, stream>>>(value, Wt_v, b_value, V);
    k_sample<<<NQ / 2, 256, 0, stream>>>(refp, offattn, V, Wt_out, b_out, out);
}

// Round 13
// 110.197 us; speedup vs baseline: 1.3447x; 1.3244x over previous
//
#include <hip/hip_runtime.h>
#include <hip/hip_bf16.h>

typedef short bf16x8 __attribute__((ext_vector_type(8)));
typedef unsigned short u16x8 __attribute__((ext_vector_type(8)));
typedef float f32x4 __attribute__((ext_vector_type(4)));

#define LQ 300
#define LV 21760
#define NQ 2400      // bs * LQ
#define MROWS 174080 // bs * LV

#define VBM 32            // rows per gemm tile
#define VGRID 512         // persistent gemm blocks (2/CU)
#define QBLK 38           // qproj blocks fused into the same launch
#define VNT (MROWS / VBM) // 5440 tiles

__device__ __forceinline__ unsigned short f2bf(float x) {
    __hip_bfloat16 h = __float2bfloat16(x);
    return *reinterpret_cast<unsigned short*>(&h);
}
__device__ __forceinline__ float bf2f(unsigned short s) {
    return __uint_as_float(((unsigned)s) << 16);
}
__device__ __forceinline__ bf16x8 cvt8(float4 a, float4 b) {
    u16x8 u;
    u[0] = f2bf(a.x); u[1] = f2bf(a.y); u[2] = f2bf(a.z); u[3] = f2bf(a.w);
    u[4] = f2bf(b.x); u[5] = f2bf(b.y); u[6] = f2bf(b.z); u[7] = f2bf(b.w);
    return (bf16x8)u;
}
__device__ __forceinline__ bf16x8 cvt8v(f32x4 a, f32x4 b) {
    u16x8 u;
    u[0] = f2bf(a[0]); u[1] = f2bf(a[1]); u[2] = f2bf(a[2]); u[3] = f2bf(a[3]);
    u[4] = f2bf(b[0]); u[5] = f2bf(b[1]); u[6] = f2bf(b[2]); u[7] = f2bf(b[3]);
    return (bf16x8)u;
}

// ---------------------------------------------------------------- K1: weight transpose+convert to bf16 [n][k]
__global__ void k_wt(const float* __restrict__ Wv, const float* __restrict__ Woff,
                     const float* __restrict__ Wattn, const float* __restrict__ Wout,
                     unsigned short* __restrict__ ws) {
    int i = blockIdx.x * 256 + threadIdx.x;   // 229376 total
    if (i < 65536) {
        int n = i >> 8, k = i & 255;
        ws[i] = f2bf(Wv[k * 256 + n]);
    } else if (i < 65536 + 98304) {
        int j = i - 65536;
        int n = j >> 8, k = j & 255;
        float s = (n < 256) ? Woff[k * 256 + n] : Wattn[k * 128 + (n - 256)];
        ws[i] = f2bf(s);
    } else {
        int j = i - 163840;
        int n = j >> 8, k = j & 255;
        ws[i] = f2bf(Wout[k * 256 + n]);
    }
}

// ---------------------------------------------------------------- K2: fused launch (R10 front — empirically best)
// blocks 0..QBLK-1 : [off|attn] = query @ [W_off|W_attn] + bias (64 rows/block)
// blocks QBLK..549 : V = bf16(value) @ Wt_v + b  (persistent dbuf pipeline)
__global__ __launch_bounds__(256, 2) void k_vgemm(
    const float* __restrict__ A, const unsigned short* __restrict__ Bt,
    const float* __restrict__ bias, unsigned short* __restrict__ V,
    const float* __restrict__ Q, const unsigned short* __restrict__ Woa,
    const float* __restrict__ b_off, const float* __restrict__ b_attn,
    float* __restrict__ offattn)
{
    __shared__ __align__(16) float buf[2][VBM * 256];   // 2 x 32 KB (gemm path only)
    const int t = threadIdx.x;
    const int lane = t & 63;
    const int wv = t >> 6;
    const int fr = lane & 15, kg = lane >> 4;

    if (blockIdx.x < QBLK) {
        // ---------------- qproj path: 4 waves, wave = 96-col group, 64 rows
        const int rowBase = blockIdx.x * 64;
        int rr[4];
#pragma unroll
        for (int m = 0; m < 4; ++m) rr[m] = min(rowBase + m * 16 + fr, NQ - 1);

        f32x4 acc[4][6];
#pragma unroll
        for (int m = 0; m < 4; m++)
#pragma unroll
            for (int n = 0; n < 6; n++) { f32x4 z = {0.f, 0.f, 0.f, 0.f}; acc[m][n] = z; }

#pragma unroll
        for (int kk = 0; kk < 8; ++kk) {
            const int kb = kk * 32 + kg * 8;
            bf16x8 a[4];
#pragma unroll
            for (int m = 0; m < 4; ++m) {
                float4 q0 = *(const float4*)(Q + (size_t)rr[m] * 256 + kb);
                float4 q1 = *(const float4*)(Q + (size_t)rr[m] * 256 + kb + 4);
                a[m] = cvt8(q0, q1);
            }
#pragma unroll
            for (int n = 0; n < 6; n++) {
                bf16x8 bb = *(const bf16x8*)(Woa + (size_t)(wv * 96 + n * 16 + fr) * 256 + kb);
#pragma unroll
                for (int m = 0; m < 4; ++m)
                    acc[m][n] = __builtin_amdgcn_mfma_f32_16x16x32_bf16(a[m], bb, acc[m][n], 0, 0, 0);
            }
        }

#pragma unroll
        for (int m = 0; m < 4; m++) {
#pragma unroll
            for (int n = 0; n < 6; n++) {
                int col = wv * 96 + n * 16 + fr;
                float bvv = (col < 256) ? b_off[col] : b_attn[col - 256];
#pragma unroll
                for (int r = 0; r < 4; r++) {
                    int row = rowBase + m * 16 + kg * 4 + r;
                    if (row < NQ) offattn[(size_t)row * 384 + col] = acc[m][n][r] + bvv;
                }
            }
        }
        return;
    }

    // ---------------- vgemm path (persistent)
    bf16x8 bw[8][4];
#pragma unroll
    for (int kk = 0; kk < 8; ++kk)
#pragma unroll
        for (int n = 0; n < 4; ++n)
            bw[kk][n] = *(const bf16x8*)(Bt + (size_t)(wv * 64 + n * 16 + fr) * 256 + kk * 32 + kg * 8);
    float bv[4];
#pragma unroll
    for (int n = 0; n < 4; ++n) bv[n] = bias[wv * 64 + n * 16 + fr];

#define VSTAGE(tile, cb)                                                                  \
    {                                                                                     \
        const char* tb = (const char*)(A + (size_t)(tile) * (VBM * 256));                 \
        _Pragma("unroll")                                                                 \
        for (int i = 0; i < 8; ++i) {                                                     \
            const int r = wv * 8 + i;                                                     \
            __builtin_amdgcn_global_load_lds(                                             \
                (const __attribute__((address_space(1))) void*)                           \
                    (tb + (size_t)r * 1024 + ((lane * 16) ^ ((r & 7) << 4))),             \
                (__attribute__((address_space(3))) void*)&buf[cb][r * 256], 16, 0, 0);    \
        }                                                                                 \
    }

    const int tb0 = (int)blockIdx.x - QBLK;
    VSTAGE(tb0, 0);

    int cur = 0;
    for (int tile = tb0; tile < VNT; tile += VGRID, cur ^= 1) {
        const int nxt = tile + VGRID;
        const bool stged = (nxt < VNT);
        if (stged) VSTAGE(nxt, cur ^ 1);
        if (tile == tb0) {
            if (stged) asm volatile("s_waitcnt vmcnt(8)" ::: "memory");
            else       asm volatile("s_waitcnt vmcnt(0)" ::: "memory");
        } else {
            if (stged) asm volatile("s_waitcnt vmcnt(12)" ::: "memory");
            else       asm volatile("s_waitcnt vmcnt(4)" ::: "memory");
        }
        __builtin_amdgcn_s_barrier();

        const float* lp = buf[cur];
        f32x4 acc[2][4];
#pragma unroll
        for (int m = 0; m < 2; ++m)
#pragma unroll
            for (int n = 0; n < 4; ++n) { f32x4 z = {0.f, 0.f, 0.f, 0.f}; acc[m][n] = z; }

#pragma unroll
        for (int kk = 0; kk < 8; ++kk) {
            bf16x8 a[2];
#pragma unroll
            for (int m = 0; m < 2; ++m) {
                const int row = m * 16 + fr;
                const int bsw = ((kk * 32 + kg * 8) * 4) ^ ((row & 7) << 4);
                f32x4 af0 = *(const f32x4*)((const char*)(lp + row * 256) + bsw);
                f32x4 af1 = *(const f32x4*)((const char*)(lp + row * 256) + (bsw ^ 16));
                a[m] = cvt8v(af0, af1);
            }
#pragma unroll
            for (int m = 0; m < 2; ++m)
#pragma unroll
                for (int n = 0; n < 4; ++n)
                    acc[m][n] = __builtin_amdgcn_mfma_f32_16x16x32_bf16(a[m], bw[kk][n], acc[m][n], 0, 0, 0);
        }

        __builtin_amdgcn_s_barrier();

        unsigned short* cp = (unsigned short*)buf[cur];  // C tile [32][264] bf16 (padded)
#pragma unroll
        for (int n = 0; n < 4; ++n)
#pragma unroll
            for (int m = 0; m < 2; ++m)
#pragma unroll
                for (int r = 0; r < 4; ++r)
                    cp[(m * 16 + kg * 4 + r) * 264 + wv * 64 + n * 16 + fr] =
                        f2bf(acc[m][n][r] + bv[n]);
        asm volatile("s_waitcnt lgkmcnt(0)" ::: "memory");
        __builtin_amdgcn_sched_barrier(0);
        __builtin_amdgcn_s_barrier();

        unsigned short* ob = V + (size_t)tile * (VBM * 256);
#pragma unroll
        for (int i = 0; i < 4; ++i) {
            const int f = i * 256 + t;
            const int row = f >> 5, col = (f & 31) * 8;
            *(u16x8*)(ob + row * 256 + col) = *(const u16x8*)&cp[row * 264 + col];
        }
        __builtin_amdgcn_s_barrier();
    }
#undef VSTAGE
}

// ---------------------------------------------------------------- K3: softmax + grid + bilinear gather (R9 back half)
// 1 block = 2 queries; 128 thr/query; each thread: 1 head, 2 channels (bf16x2 loads).
__global__ __launch_bounds__(256) void k_sample(
    const float* __restrict__ refp, const float* __restrict__ offattn,
    const unsigned short* __restrict__ V, unsigned short* __restrict__ att)
{
    __shared__ float aw[2][128], gx[2][128], gy[2][128];
    const int t = threadIdx.x;
    const int jj = t >> 7;               // query slot in block
    const int tt = t & 127;
    const int row = blockIdx.x * 2 + jj; // global query index
    const int b = row / LQ;
    const float* oa = offattn + (size_t)row * 384;

    {   // setup: thread (jj,tt) handles point tt of query jj
        float logit = oa[256 + tt];
        float m = logit;
        m = fmaxf(m, __shfl_xor(m, 1));
        m = fmaxf(m, __shfl_xor(m, 2));
        m = fmaxf(m, __shfl_xor(m, 4));
        m = fmaxf(m, __shfl_xor(m, 8));
        float e = __expf(logit - m);
        float s = e;
        s += __shfl_xor(s, 1);
        s += __shfl_xor(s, 2);
        s += __shfl_xor(s, 4);
        s += __shfl_xor(s, 8);
        aw[jj][tt] = e / s;
        const int l = (tt >> 2) & 3;
        const float Wl = (l == 0) ? 128.f : (l == 1) ? 64.f : (l == 2) ? 32.f : 16.f;
        float ox = oa[2 * tt], oy = oa[2 * tt + 1];
        const float* rp = refp + ((size_t)row * 4 + l) * 4;
        gx[jj][tt] = (rp[0] + ox * 0.125f * rp[2]) * Wl - 0.5f;
        gy[jj][tt] = (rp[1] + oy * 0.125f * rp[3]) * Wl - 0.5f;
    }
    __syncthreads();

    const int h = tt >> 4;                  // head
    const int ch = h * 32 + (tt & 15) * 2;  // channel pair base
    float acc0 = 0.f, acc1 = 0.f;
#pragma unroll 4
    for (int p = 0; p < 16; p++) {
        const int l = p >> 2;
        const int Wl = (l == 0) ? 128 : (l == 1) ? 64 : (l == 2) ? 32 : 16;
        const int S  = (l == 0) ? 0 : (l == 1) ? 16384 : (l == 2) ? 20480 : 21504;
        int pt = h * 16 + p;
        float a  = aw[jj][pt];
        float sx = gx[jj][pt], sy = gy[jj][pt];
        float x0f = floorf(sx), y0f = floorf(sy);
        int   x0 = (int)x0f, y0 = (int)y0f;
        float wx1 = sx - x0f, wy1 = sy - y0f;
        float wx0 = 1.f - wx1, wy0 = 1.f - wy1;
        bool vx0 = (unsigned)x0 < (unsigned)Wl;
        bool vx1 = (unsigned)(x0 + 1) < (unsigned)Wl;
        bool vy0 = (unsigned)y0 < (unsigned)Wl;
        bool vy1 = (unsigned)(y0 + 1) < (unsigned)Wl;
        float p00x = 0.f, p00y = 0.f, p01x = 0.f, p01y = 0.f;
        float p10x = 0.f, p10y = 0.f, p11x = 0.f, p11y = 0.f;
        size_t pixBase = (size_t)b * LV + S;
        if (vy0) {
            size_t rb = (pixBase + (size_t)y0 * Wl) * 256 + ch;
            if (vx0) { unsigned u = *(const unsigned*)(V + rb + (size_t)x0 * 256);
                       p00x = bf2f((unsigned short)u); p00y = bf2f((unsigned short)(u >> 16)); }
            if (vx1) { unsigned u = *(const unsigned*)(V + rb + (size_t)x0 * 256 + 256);
                       p01x = bf2f((unsigned short)u); p01y = bf2f((unsigned short)(u >> 16)); }
        }
        if (vy1) {
            size_t rb = (pixBase + (size_t)(y0 + 1) * Wl) * 256 + ch;
            if (vx0) { unsigned u = *(const unsigned*)(V + rb + (size_t)x0 * 256);
                       p10x = bf2f((unsigned short)u); p10y = bf2f((unsigned short)(u >> 16)); }
            if (vx1) { unsigned u = *(const unsigned*)(V + rb + (size_t)x0 * 256 + 256);
                       p11x = bf2f((unsigned short)u); p11y = bf2f((unsigned short)(u >> 16)); }
        }
        acc0 += a * (wy0 * (wx0 * p00x + wx1 * p01x) + wy1 * (wx0 * p10x + wx1 * p11x));
        acc1 += a * (wy0 * (wx0 * p00y + wx1 * p01y) + wy1 * (wx0 * p10y + wx1 * p11y));
    }
    unsigned short o2[2] = { f2bf(acc0), f2bf(acc1) };
    *(unsigned*)(att + (size_t)row * 256 + ch) = *(const unsigned*)o2;
}

// ---------------------------------------------------------------- K4: out = att @ W_out + b_out (M=2400,N=256,K=256) MFMA
__global__ __launch_bounds__(256) void k_outproj(
    const unsigned short* __restrict__ att, const unsigned short* __restrict__ Wout,
    const float* __restrict__ b_out, float* __restrict__ out)
{
    const int t = threadIdx.x;
    const int lane = t & 63;
    const int wc = t >> 6;
    const int fr = lane & 15, kg = lane >> 4;
    const int rowBase = blockIdx.x * 64;

    f32x4 acc[4][4];
#pragma unroll
    for (int m = 0; m < 4; m++)
#pragma unroll
        for (int n = 0; n < 4; n++) { f32x4 z = {0.f, 0.f, 0.f, 0.f}; acc[m][n] = z; }

#pragma unroll
    for (int kk = 0; kk < 8; ++kk) {
        const int kb = kk * 32 + kg * 8;
        bf16x8 a[4], bb[4];
#pragma unroll
        for (int m = 0; m < 4; m++) {
            int row = min(rowBase + m * 16 + fr, NQ - 1);
            a[m] = *(const bf16x8*)(att + (size_t)row * 256 + kb);
        }
#pragma unroll
        for (int n = 0; n < 4; n++)
            bb[n] = *(const bf16x8*)(Wout + (size_t)(wc * 64 + n * 16 + fr) * 256 + kb);
#pragma unroll
        for (int m = 0; m < 4; m++)
#pragma unroll
            for (int n = 0; n < 4; n++)
                acc[m][n] = __builtin_amdgcn_mfma_f32_16x16x32_bf16(a[m], bb[n], acc[m][n], 0, 0, 0);
    }

#pragma unroll
    for (int m = 0; m < 4; m++) {
#pragma unroll
        for (int n = 0; n < 4; n++) {
            int col = wc * 64 + n * 16 + fr;
            float bvv = b_out[col];
#pragma unroll
            for (int r = 0; r < 4; r++) {
                int row = rowBase + m * 16 + kg * 4 + r;
                if (row < NQ) out[(size_t)row * 256 + col] = acc[m][n][r] + bvv;
            }
        }
    }
}

// ----------------------------------------------------------------
extern "C" void kernel_launch(void* const* d_in, const int* in_sizes, int n_in,
                              void* d_out, int out_size, void* d_ws, size_t ws_size,
                              hipStream_t stream) {
    const float* query   = (const float*)d_in[0];
    const float* refp    = (const float*)d_in[1];
    const float* value   = (const float*)d_in[2];
    const float* W_value = (const float*)d_in[3];
    const float* b_value = (const float*)d_in[4];
    const float* W_off   = (const float*)d_in[5];
    const float* b_off   = (const float*)d_in[6];
    const float* W_attn  = (const float*)d_in[7];
    const float* b_attn  = (const float*)d_in[8];
    const float* W_out   = (const float*)d_in[9];
    const float* b_out   = (const float*)d_in[10];
    float* out = (float*)d_out;

    unsigned short* wsu   = (unsigned short*)d_ws;
    unsigned short* Wt_v  = wsu;                       // 65536
    unsigned short* Wt_oa = Wt_v + 65536;              // 98304
    unsigned short* Wt_out= Wt_oa + 98304;             // 65536
    unsigned short* V     = Wt_out + 65536;            // 174080*256 bf16
    float* offattn = (float*)(V + (size_t)MROWS * 256);     // 2400*384 f32
    unsigned short* att = (unsigned short*)(offattn + (size_t)NQ * 384); // 2400*256 bf16

    k_wt<<<896, 256, 0, stream>>>(W_value, W_off, W_attn, W_out, wsu);
    k_vgemm<<<VGRID + QBLK, 256, 0, stream>>>(value, Wt_v, b_value, V,
                                              query, Wt_oa, b_off, b_attn, offattn);
    k_sample<<<NQ / 2, 256, 0, stream>>>(refp, offattn, V, att);
    k_outproj<<<38, 256, 0, stream>>>(att, Wt_out, b_out, out);
}